// Round 4
// baseline (241.534 us; speedup 1.0000x reference)
//
#include <hip/hip_runtime.h>

typedef __attribute__((ext_vector_type(8))) short short8;
typedef __attribute__((ext_vector_type(4))) short short4v;
typedef __attribute__((ext_vector_type(4))) float floatx4;

__device__ __forceinline__ unsigned short f2bf(float f) {
    unsigned int u = __float_as_uint(f);
    u += 0x7FFFu + ((u >> 16) & 1u);   // round-to-nearest-even
    return (unsigned short)(u >> 16);
}
__device__ __forceinline__ float bf2f(unsigned short s) {
    return __uint_as_float(((unsigned int)s) << 16);
}
__device__ __forceinline__ float sigmoidf(float x) {
    return 1.f / (1.f + __expf(-x));
}

// Prologue: Wf|Wa fp32 [256,512] -> bf16, MFMA fragment order (works as A- or
// B-operand: lane slot lk*16+l15 holds W[d = g*16+l15][k = ks*32+lk*8 .. +8]).
// short8 index = (g*16 + ks)*64 + lane.  g<16 -> Wf, g>=16 -> Wa.
__global__ __launch_bounds__(256)
void convert_w_kernel(const float* __restrict__ Wf,
                      const float* __restrict__ Wa,
                      short* __restrict__ wswz)
{
    int id = blockIdx.x * 256 + threadIdx.x;       // 32768 total
    int slot = id & 63;
    int ks   = (id >> 6) & 15;
    int g    = id >> 10;
    int l15  = slot & 15, lk = slot >> 4;
    const float* base = (g < 16) ? (Wf + (long)(g * 16 + l15) * 512)
                                 : (Wa + (long)((g - 16) * 16 + l15) * 512);
    const float* src = base + ks * 32 + lk * 8;
    floatx4 w0 = *(const floatx4*)src;
    floatx4 w1 = *(const floatx4*)(src + 4);
    short8 o;
    o[0] = (short)f2bf(w0[0]); o[1] = (short)f2bf(w0[1]);
    o[2] = (short)f2bf(w0[2]); o[3] = (short)f2bf(w0[3]);
    o[4] = (short)f2bf(w1[0]); o[5] = (short)f2bf(w1[1]);
    o[6] = (short)f2bf(w1[2]); o[7] = (short)f2bf(w1[3]);
    *(short8*)(wswz + (long)id * 8) = o;
}

// Mark updated rows.
__global__ __launch_bounds__(256)
void mark_kernel(const int* __restrict__ ei, const int* __restrict__ ti,
                 unsigned char* __restrict__ flags, int n)
{
    int i = blockIdx.x * 256 + threadIdx.x;
    if (i < n) flags[64 * ei[i] + ti[i]] = 1;
}

// Copy rows NOT updated (one wave per row; wave-uniform flag branch).
__global__ __launch_bounds__(256)
void copy_rest_kernel(const float* __restrict__ flat,
                      const unsigned char* __restrict__ flags,
                      float* __restrict__ out, int nrows)
{
    const int lane = threadIdx.x & 63;
    const int w0   = (blockIdx.x * 256 + threadIdx.x) >> 6;
    const int nw   = (gridDim.x * 256) >> 6;
    for (int row = w0; row < nrows; row += nw) {
        if (flags[row]) continue;
        const floatx4* s = (const floatx4*)(flat + (long)row * 256);
        floatx4*       o = (floatx4*)(out + (long)row * 256);
        o[lane] = s[lane];
    }
}

// Fused gather + bf16 GEMM (Z^T: A=weights, B=concat rows) + sigmoid gates +
// gated combine + scatter.
// Block: 512 threads (8 waves), BM=64 rows, LDS 66.5KB -> 2 blocks/CU.
// Wave w owns d in [32w,32w+32) for BOTH gates x all 64 rows (acc[4][4]).
// D layout: col = m (lane&15), row = d (lk*4+j) -> lane owns 4 CONSECUTIVE d
// per fragment -> b64 LDS reads + dwordx4 stores in epilogue.
__global__ __launch_bounds__(512, 4)
void gate_gemm_kernel(const float* __restrict__ flat,   // [262144,256]
                      const float* __restrict__ syms,   // [20000,256]
                      const float* __restrict__ bfb,    // [256]
                      const float* __restrict__ bab,    // [256]
                      const int* __restrict__ expr_idx,
                      const int* __restrict__ token_idx,
                      const int* __restrict__ sym_idx,
                      const short* __restrict__ wswz,   // bf16 fragment weights
                      float* __restrict__ out)          // [262144,256]
{
    __shared__ __align__(16) short A_lds[64][520];  // 64 rows x 512 k, +8 pad
    __shared__ int rowbuf[64];
    __shared__ int symbuf[64];

    const int tid  = threadIdx.x;
    const int occ0 = blockIdx.x * 64;

    if (tid < 64) {
        int occ = occ0 + tid;
        rowbuf[tid] = 64 * expr_idx[occ] + token_idx[occ];
        symbuf[tid] = sym_idx[occ];
    }
    __syncthreads();

    // ---- stage full A tile: 8 threads/row, fp32 gather -> bf16 LDS ----
    {
        const int srow = tid >> 3;     // 0..63
        const int se   = tid & 7;
        const float* prow = flat + (long)rowbuf[srow] * 256;
        const float* urow = syms + (long)symbuf[srow] * 256;
        #pragma unroll
        for (int it = 0; it < 8; ++it) {
            const int k = (se + it * 8) * 4;       // 0..252, covers 0..255
            floatx4 v = *(const floatx4*)(prow + k);
            short4v sv;
            sv[0] = (short)f2bf(v[0]); sv[1] = (short)f2bf(v[1]);
            sv[2] = (short)f2bf(v[2]); sv[3] = (short)f2bf(v[3]);
            *(short4v*)&A_lds[srow][k] = sv;
        }
        #pragma unroll
        for (int it = 0; it < 8; ++it) {
            const int k = (se + it * 8) * 4;
            floatx4 v = *(const floatx4*)(urow + k);
            short4v sv;
            sv[0] = (short)f2bf(v[0]); sv[1] = (short)f2bf(v[1]);
            sv[2] = (short)f2bf(v[2]); sv[3] = (short)f2bf(v[3]);
            *(short4v*)&A_lds[srow][256 + k] = sv;
        }
    }
    __syncthreads();

    const int lane = tid & 63;
    const int wv   = tid >> 6;    // 0..7
    const int l15  = lane & 15;
    const int lk   = lane >> 4;   // 0..3

    floatx4 acc[4][4];            // [m-chunk][c: 0,1=forget, 2,3=add]
    #pragma unroll
    for (int mi = 0; mi < 4; ++mi)
        #pragma unroll
        for (int c = 0; c < 4; ++c)
            acc[mi][c] = (floatx4){0.f, 0.f, 0.f, 0.f};

    const short8* wsv = (const short8*)wswz;

    #pragma unroll
    for (int ks = 0; ks < 16; ++ks) {
        short8 cb[4];   // concat B-fragments (cols = m)
        #pragma unroll
        for (int mi = 0; mi < 4; ++mi)
            cb[mi] = *(const short8*)&A_lds[mi * 16 + l15][ks * 32 + lk * 8];

        #pragma unroll
        for (int c = 0; c < 4; ++c) {
            const int g = (c < 2) ? (wv * 2 + c) : (16 + wv * 2 + (c - 2));
            short8 wf = wsv[(g * 16 + ks) * 64 + lane];
            #pragma unroll
            for (int mi = 0; mi < 4; ++mi)
                acc[mi][c] = __builtin_amdgcn_mfma_f32_16x16x32_bf16(
                    wf, cb[mi], acc[mi][c], 0, 0, 0);
        }
    }

    // ---- epilogue: lane owns m = mi*16+l15, d = 32wv+16c+lk*4 .. +3 ----
    #pragma unroll
    for (int c = 0; c < 2; ++c) {
        const int d0 = wv * 32 + c * 16 + lk * 4;
        const floatx4 bfv = *(const floatx4*)(bfb + d0);
        const floatx4 bav = *(const floatx4*)(bab + d0);
        #pragma unroll
        for (int mi = 0; mi < 4; ++mi) {
            const int m = mi * 16 + l15;
            short4v pv = *(const short4v*)&A_lds[m][d0];
            short4v uv = *(const short4v*)&A_lds[m][256 + d0];
            floatx4 res;
            #pragma unroll
            for (int j = 0; j < 4; ++j) {
                float fg = sigmoidf(acc[mi][c][j]     + bfv[j]);
                float ag = sigmoidf(acc[mi][c + 2][j] + bav[j]);
                res[j] = fg * bf2f((unsigned short)pv[j])
                       + ag * bf2f((unsigned short)uv[j]);
            }
            *(floatx4*)(out + (long)rowbuf[m] * 256 + d0) = res;
        }
    }
}

extern "C" void kernel_launch(void* const* d_in, const int* in_sizes, int n_in,
                              void* d_out, int out_size, void* d_ws, size_t ws_size,
                              hipStream_t stream) {
    const float* flat = (const float*)d_in[0];
    const float* syms = (const float*)d_in[1];
    const float* Wf   = (const float*)d_in[2];
    const float* bf   = (const float*)d_in[3];
    const float* Wa   = (const float*)d_in[4];
    const float* ba   = (const float*)d_in[5];
    const int* ei     = (const int*)d_in[6];
    const int* ti     = (const int*)d_in[7];
    const int* si     = (const int*)d_in[8];
    float* out        = (float*)d_out;

    short* wswz          = (short*)d_ws;                        // 512 KB
    unsigned char* flags = (unsigned char*)d_ws + 512 * 1024;   // 256 KB

    const int n_occ = in_sizes[6];        // 131072
    const int nrows = out_size / 256;     // 262144

    hipMemsetAsync(flags, 0, nrows, stream);
    mark_kernel<<<(n_occ + 255) / 256, 256, 0, stream>>>(ei, ti, flags, n_occ);

    convert_w_kernel<<<128, 256, 0, stream>>>(Wf, Wa, wswz);

    gate_gemm_kernel<<<n_occ / 64, 512, 0, stream>>>(flat, syms, bf, ba,
                                                     ei, ti, si, wswz, out);

    copy_rest_kernel<<<2048, 256, 0, stream>>>(flat, flags, out, nrows);
}